// Round 5
// baseline (293.659 us; speedup 1.0000x reference)
//
#include <hip/hip_runtime.h>
#include <math.h>

#define N_ENT   50000
#define N_REL   500
#define N_EDGE  800000
#define H       96
#define BN_EPS  1e-5f
#define SCAN_B  1024
#define NBLK    ((N_ENT + SCAN_B - 1) / SCAN_B)   // 49 <= 64

// ---- zero a region of workspace ----
__global__ void k_zero(unsigned* __restrict__ p, int n) {
    int i = blockIdx.x * blockDim.x + threadIdx.x;
    if (i < n) p[i] = 0u;
}

// ---- relW = rel_emb @ W  (500 x 96 x 96), W staged in LDS ----
__global__ __launch_bounds__(256) void k_relw(
        const float* __restrict__ rel, const float* __restrict__ W,
        float* __restrict__ relW) {
    __shared__ float Ws[H * H];
    for (int i = threadIdx.x; i < H * H; i += 256) Ws[i] = W[i];
    __syncthreads();
    int t = blockIdx.x * 256 + threadIdx.x;
    if (t >= N_REL * H) return;
    int r = t / H;
    int c = t - r * H;
    const float4* rr = (const float4*)(rel + (size_t)r * H);
    float acc = 0.0f;
#pragma unroll
    for (int i = 0; i < H / 4; ++i) {
        float4 a = rr[i];
        acc += a.x * Ws[(4 * i + 0) * H + c];
        acc += a.y * Ws[(4 * i + 1) * H + c];
        acc += a.z * Ws[(4 * i + 2) * H + c];
        acc += a.w * Ws[(4 * i + 3) * H + c];
    }
    relW[t] = acc;
}

// ---- histogram: deg[dst[e]]++ , 4 edges / thread via int4 ----
__global__ __launch_bounds__(256) void k_hist(
        const int* __restrict__ dst, int* __restrict__ deg) {
    int i = blockIdx.x * 256 + threadIdx.x;
    if (i >= N_EDGE / 4) return;              // 800000 % 4 == 0
    int4 d = ((const int4*)dst)[i];
    atomicAdd(deg + d.x, 1);
    atomicAdd(deg + d.y, 1);
    atomicAdd(deg + d.z, 1);
    atomicAdd(deg + d.w, 1);
}

// ---- scan phase 1: per-block LDS Hillis-Steele, exclusive within block ----
__global__ __launch_bounds__(SCAN_B) void k_scan1(
        const int* __restrict__ deg, int* __restrict__ row_ptr,
        int* __restrict__ blk_sum) {
    __shared__ int sh[SCAN_B];
    int t = threadIdx.x;
    int g = blockIdx.x * SCAN_B + t;
    int v = (g < N_ENT) ? deg[g] : 0;
    sh[t] = v;
    __syncthreads();
    for (int off = 1; off < SCAN_B; off <<= 1) {
        int u = (t >= off) ? sh[t - off] : 0;
        __syncthreads();
        sh[t] += u;
        __syncthreads();
    }
    if (g < N_ENT) row_ptr[g] = sh[t] - v;   // exclusive
    if (t == SCAN_B - 1) blk_sum[blockIdx.x] = sh[t];
}

// ---- scan phase 2: one wave shuffle-scans the 49 block sums ----
__global__ __launch_bounds__(64) void k_scan2(int* __restrict__ blk_sum) {
    int t = threadIdx.x;
    int v = (t < NBLK) ? blk_sum[t] : 0;
    for (int off = 1; off < 64; off <<= 1) {
        int u = __shfl_up(v, off);
        if (t >= off) v += u;
    }
    int ex = __shfl_up(v, 1);
    if (t == 0) ex = 0;
    if (t < NBLK) blk_sum[t] = ex;
}

// ---- scan phase 3: add block offsets ----
__global__ __launch_bounds__(SCAN_B) void k_scan3(
        int* __restrict__ row_ptr, const int* __restrict__ blk_sum) {
    int g = blockIdx.x * SCAN_B + threadIdx.x;
    if (g < N_ENT) row_ptr[g] += blk_sum[blockIdx.x];
}

// ---- fused: 8 lanes/edge score = rel_row . ent_row; lane0 scatters payload ----
__global__ __launch_bounds__(256) void k_score_bucket(
        const float* __restrict__ ent, const float* __restrict__ rel,
        const int* __restrict__ rel_id, const int* __restrict__ dst,
        const int* __restrict__ row_ptr, int* __restrict__ cursor,
        int2* __restrict__ pay) {
    int tid = blockIdx.x * 256 + threadIdx.x;
    int e = tid >> 3;
    int q = tid & 7;
    if (e >= N_EDGE) return;
    int d = dst[e];
    int rid = rel_id[e];
    const float4* r = (const float4*)(rel + (size_t)rid * H);
    const float4* v = (const float4*)(ent + (size_t)d * H);
    float acc = 0.0f;
#pragma unroll
    for (int i = 0; i < 3; ++i) {            // lane q reads float4 q+8i
        float4 a = r[q + 8 * i];
        float4 b = v[q + 8 * i];
        acc += a.x * b.x + a.y * b.y + a.z * b.z + a.w * b.w;
    }
    acc += __shfl_xor(acc, 1);
    acc += __shfl_xor(acc, 2);
    acc += __shfl_xor(acc, 4);
    if (q == 0) {
        int pos = row_ptr[d] + atomicAdd(cursor + d, 1);
        pay[pos] = make_int2(rid, __float_as_int(acc));
    }
}

// ---- per node: max + exp-sum over segment; w in place, inv_sum per node ----
__global__ __launch_bounds__(256) void k_alpha(
        const int* __restrict__ row_ptr, const int* __restrict__ deg,
        int2* __restrict__ pay, float* __restrict__ inv_sum) {
    int n = blockIdx.x * 256 + threadIdx.x;
    if (n >= N_ENT) return;
    int start = row_ptr[n];
    int cnt = deg[n];
    if (cnt == 0) { inv_sum[n] = 0.0f; return; }
    float m = -INFINITY;
    for (int j = 0; j < cnt; ++j)
        m = fmaxf(m, __int_as_float(pay[start + j].y));
    float s = 0.0f;
    for (int j = 0; j < cnt; ++j) {
        float w = expf(__int_as_float(pay[start + j].y) - m);
        pay[start + j].y = __float_as_int(w);
        s += w;
    }
    inv_sum[n] = 1.0f / s;
}

// ---- per (node, dim): out = inv_sum * sum_j w_j * relW[rid_j][dim] ----
__global__ __launch_bounds__(256) void k_aggregate(
        const int2* __restrict__ pay, const int* __restrict__ row_ptr,
        const int* __restrict__ deg, const float* __restrict__ inv_sum,
        const float* __restrict__ relW, float* __restrict__ out) {
    int t = blockIdx.x * 256 + threadIdx.x;
    if (t >= N_ENT * H) return;
    int n = t / H;
    int dim = t - n * H;
    int start = row_ptr[n];
    int cnt = deg[n];
    float acc = 0.0f;
    int j = 0;
    for (; j + 4 <= cnt; j += 4) {
        int2 p0 = pay[start + j + 0];
        int2 p1 = pay[start + j + 1];
        int2 p2 = pay[start + j + 2];
        int2 p3 = pay[start + j + 3];
        float v0 = relW[p0.x * H + dim];
        float v1 = relW[p1.x * H + dim];
        float v2 = relW[p2.x * H + dim];
        float v3 = relW[p3.x * H + dim];
        acc += __int_as_float(p0.y) * v0 + __int_as_float(p1.y) * v1
             + __int_as_float(p2.y) * v2 + __int_as_float(p3.y) * v3;
    }
    for (; j < cnt; ++j) {
        int2 p = pay[start + j];
        acc += __int_as_float(p.y) * relW[p.x * H + dim];
    }
    out[t] = acc * inv_sum[n];
}

// ---- per-column sum / sumsq with block-private accumulation ----
__global__ void k_bnstats(const float* __restrict__ out,
                          float* __restrict__ bn_sum, float* __restrict__ bn_sumsq) {
    int d = threadIdx.x;          // blockDim.x = 128, only d < 96 active
    if (d >= H) return;
    float s = 0.0f, ss = 0.0f;
    for (int n = blockIdx.x; n < N_ENT; n += gridDim.x) {
        float v = out[(size_t)n * H + d];
        s += v;
        ss += v * v;
    }
    atomicAdd(bn_sum + d, s);
    atomicAdd(bn_sumsq + d, ss);
}

// ---- apply BN (batch stats) + tanh in place ----
__global__ __launch_bounds__(256) void k_bnapply(
        float* __restrict__ out, const float* __restrict__ bn_sum,
        const float* __restrict__ bn_sumsq, const float* __restrict__ gamma,
        const float* __restrict__ beta) {
    int t = blockIdx.x * 256 + threadIdx.x;
    if (t >= N_ENT * H) return;
    int d = t % H;
    const float inv_n = 1.0f / (float)N_ENT;
    float mu = bn_sum[d] * inv_n;
    float var = bn_sumsq[d] * inv_n - mu * mu;
    float x = (out[t] - mu) * rsqrtf(var + BN_EPS) * gamma[d] + beta[d];
    out[t] = tanhf(x);
}

extern "C" void kernel_launch(void* const* d_in, const int* in_sizes, int n_in,
                              void* d_out, int out_size, void* d_ws, size_t ws_size,
                              hipStream_t stream) {
    const float* ent   = (const float*)d_in[0];   // [50000,96]
    const float* rel   = (const float*)d_in[1];   // [500,96]
    const float* W     = (const float*)d_in[2];   // [96,96]
    const float* gamma = (const float*)d_in[3];   // [96]
    const float* beta  = (const float*)d_in[4];   // [96]
    const int* rel_id  = (const int*)d_in[5];     // [800000]
    const int* dst     = (const int*)d_in[6];     // [800000]
    float* out = (float*)d_out;                   // [50000,96] fp32

    // ws layout (4B units):
    // pay int2[E] (2E) | row_ptr [N] | inv_sum [N] |
    // ZERO{ deg [N] | cursor [N] | bn_sum [H] | bn_sumsq [H] } |
    // relW [500*96] | blk_sum [NBLK]
    float* ws       = (float*)d_ws;
    int2*  pay      = (int2*)ws;
    int*   row_ptr  = (int*)(ws + 2 * N_EDGE);
    float* inv_sum  = ws + 2 * N_EDGE + N_ENT;
    int*   zbase    = (int*)(ws + 2 * N_EDGE + 2 * N_ENT);
    int*   deg      = zbase;
    int*   cursor   = zbase + N_ENT;
    float* bn_sum   = (float*)(zbase + 2 * N_ENT);
    float* bn_sumsq = bn_sum + H;
    float* relW     = bn_sumsq + H;
    int*   blk_sum  = (int*)(relW + N_REL * H);

    const int zcount = 2 * N_ENT + 2 * H;
    k_zero<<<(zcount + 255) / 256, 256, 0, stream>>>((unsigned*)zbase, zcount);

    k_relw <<<(N_REL * H + 255) / 256, 256, 0, stream>>>(rel, W, relW);
    k_hist <<<(N_EDGE / 4 + 255) / 256, 256, 0, stream>>>(dst, deg);
    k_scan1<<<NBLK, SCAN_B, 0, stream>>>(deg, row_ptr, blk_sum);
    k_scan2<<<1, 64, 0, stream>>>(blk_sum);
    k_scan3<<<NBLK, SCAN_B, 0, stream>>>(row_ptr, blk_sum);
    k_score_bucket<<<(N_EDGE * 8 + 255) / 256, 256, 0, stream>>>(
        ent, rel, rel_id, dst, row_ptr, cursor, pay);
    k_alpha<<<(N_ENT + 255) / 256, 256, 0, stream>>>(row_ptr, deg, pay, inv_sum);
    k_aggregate<<<(N_ENT * H + 255) / 256, 256, 0, stream>>>(
        pay, row_ptr, deg, inv_sum, relW, out);
    k_bnstats<<<512, 128, 0, stream>>>(out, bn_sum, bn_sumsq);
    k_bnapply<<<(N_ENT * H + 255) / 256, 256, 0, stream>>>(out, bn_sum, bn_sumsq, gamma, beta);
}

// Round 6
// 292.847 us; speedup vs baseline: 1.0028x; 1.0028x over previous
//
#include <hip/hip_runtime.h>
#include <math.h>

#define N_ENT   50000
#define N_REL   500
#define N_EDGE  800000
#define H       96
#define BN_EPS  1e-5f
#define SCAN_B  1024
#define NBLK    ((N_ENT + SCAN_B - 1) / SCAN_B)   // 49 <= 64

// ---- zero a region of workspace ----
__global__ void k_zero(unsigned* __restrict__ p, int n) {
    int i = blockIdx.x * blockDim.x + threadIdx.x;
    if (i < n) p[i] = 0u;
}

// ---- relW = rel_emb @ W  (500 x 96 x 96), W staged in LDS ----
__global__ __launch_bounds__(256) void k_relw(
        const float* __restrict__ rel, const float* __restrict__ W,
        float* __restrict__ relW) {
    __shared__ float Ws[H * H];
    for (int i = threadIdx.x; i < H * H; i += 256) Ws[i] = W[i];
    __syncthreads();
    int t = blockIdx.x * 256 + threadIdx.x;
    if (t >= N_REL * H) return;
    int r = t / H;
    int c = t - r * H;
    const float4* rr = (const float4*)(rel + (size_t)r * H);
    float acc = 0.0f;
#pragma unroll
    for (int i = 0; i < H / 4; ++i) {
        float4 a = rr[i];
        acc += a.x * Ws[(4 * i + 0) * H + c];
        acc += a.y * Ws[(4 * i + 1) * H + c];
        acc += a.z * Ws[(4 * i + 2) * H + c];
        acc += a.w * Ws[(4 * i + 3) * H + c];
    }
    relW[t] = acc;
}

// ---- histogram: deg[dst[e]]++ , 4 edges / thread via int4 ----
__global__ __launch_bounds__(256) void k_hist(
        const int* __restrict__ dst, int* __restrict__ deg) {
    int i = blockIdx.x * 256 + threadIdx.x;
    if (i >= N_EDGE / 4) return;              // 800000 % 4 == 0
    int4 d = ((const int4*)dst)[i];
    atomicAdd(deg + d.x, 1);
    atomicAdd(deg + d.y, 1);
    atomicAdd(deg + d.z, 1);
    atomicAdd(deg + d.w, 1);
}

// ---- scan phase 1: per-block LDS Hillis-Steele, exclusive within block ----
__global__ __launch_bounds__(SCAN_B) void k_scan1(
        const int* __restrict__ deg, int* __restrict__ row_ptr,
        int* __restrict__ blk_sum) {
    __shared__ int sh[SCAN_B];
    int t = threadIdx.x;
    int g = blockIdx.x * SCAN_B + t;
    int v = (g < N_ENT) ? deg[g] : 0;
    sh[t] = v;
    __syncthreads();
    for (int off = 1; off < SCAN_B; off <<= 1) {
        int u = (t >= off) ? sh[t - off] : 0;
        __syncthreads();
        sh[t] += u;
        __syncthreads();
    }
    if (g < N_ENT) row_ptr[g] = sh[t] - v;   // exclusive
    if (t == SCAN_B - 1) blk_sum[blockIdx.x] = sh[t];
}

// ---- scan phase 2: one wave shuffle-scans the 49 block sums ----
__global__ __launch_bounds__(64) void k_scan2(int* __restrict__ blk_sum) {
    int t = threadIdx.x;
    int v = (t < NBLK) ? blk_sum[t] : 0;
    for (int off = 1; off < 64; off <<= 1) {
        int u = __shfl_up(v, off);
        if (t >= off) v += u;
    }
    int ex = __shfl_up(v, 1);
    if (t == 0) ex = 0;
    if (t < NBLK) blk_sum[t] = ex;
}

// ---- scan phase 3: add block offsets ----
__global__ __launch_bounds__(SCAN_B) void k_scan3(
        int* __restrict__ row_ptr, const int* __restrict__ blk_sum) {
    int g = blockIdx.x * SCAN_B + threadIdx.x;
    if (g < N_ENT) row_ptr[g] += blk_sum[blockIdx.x];
}

// ---- fused: 8 lanes/edge score = rel_row . ent_row; lane0 scatters payload ----
__global__ __launch_bounds__(256) void k_score_bucket(
        const float* __restrict__ ent, const float* __restrict__ rel,
        const int* __restrict__ rel_id, const int* __restrict__ dst,
        const int* __restrict__ row_ptr, int* __restrict__ cursor,
        int2* __restrict__ pay) {
    int tid = blockIdx.x * 256 + threadIdx.x;
    int e = tid >> 3;
    int q = tid & 7;
    if (e >= N_EDGE) return;
    int d = dst[e];
    int rid = rel_id[e];
    const float4* r = (const float4*)(rel + (size_t)rid * H);
    const float4* v = (const float4*)(ent + (size_t)d * H);
    float acc = 0.0f;
#pragma unroll
    for (int i = 0; i < 3; ++i) {            // lane q reads float4 q+8i
        float4 a = r[q + 8 * i];
        float4 b = v[q + 8 * i];
        acc += a.x * b.x + a.y * b.y + a.z * b.z + a.w * b.w;
    }
    acc += __shfl_xor(acc, 1);
    acc += __shfl_xor(acc, 2);
    acc += __shfl_xor(acc, 4);
    if (q == 0) {
        int pos = row_ptr[d] + atomicAdd(cursor + d, 1);
        pay[pos] = make_int2(rid, __float_as_int(acc));
    }
}

// ---- one wave per node: softmax (shuffle-reduce) + weighted relW sum ----
__global__ __launch_bounds__(256) void k_node(
        const int2* __restrict__ pay, const int* __restrict__ row_ptr,
        const int* __restrict__ deg, const float* __restrict__ relW,
        float* __restrict__ out) {
    int gtid = blockIdx.x * 256 + threadIdx.x;
    int n = gtid >> 6;                 // one wave per node
    int lane = threadIdx.x & 63;
    if (n >= N_ENT) return;
    int start = row_ptr[n];
    int cnt = deg[n];

    // pass 1: wave-max of scores
    float m = -INFINITY;
    for (int j = lane; j < cnt; j += 64)
        m = fmaxf(m, __int_as_float(pay[start + j].y));
#pragma unroll
    for (int off = 1; off < 64; off <<= 1)
        m = fmaxf(m, __shfl_xor(m, off));

    // pass 2: wave-sum of exp
    float s = 0.0f;
    for (int j = lane; j < cnt; j += 64)
        s += __expf(__int_as_float(pay[start + j].y) - m);
#pragma unroll
    for (int off = 1; off < 64; off <<= 1)
        s += __shfl_xor(s, off);
    float inv = 1.0f / s;

    // pass 3: accumulate. chunk of 64 edges in registers, broadcast via shfl.
    float2 acc = make_float2(0.0f, 0.0f);
    for (int base = 0; base < cnt; base += 64) {
        int j = base + lane;
        float w = 0.0f;
        int rid = 0;
        if (j < cnt) {
            int2 p = pay[start + j];
            rid = p.x;
            w = __expf(__int_as_float(p.y) - m) * inv;
        }
        int lim = min(64, cnt - base);
        for (int k = 0; k < lim; ++k) {
            float a = __shfl(w, k);
            int rr = __shfl(rid, k);
            if (lane < H / 2) {
                float2 f = ((const float2*)(relW + (size_t)rr * H))[lane];
                acc.x += a * f.x;
                acc.y += a * f.y;
            }
        }
    }
    if (lane < H / 2)
        ((float2*)(out + (size_t)n * H))[lane] = acc;
}

// ---- BN stats: one wave per row-group, float2 lanes, 8 atomics/lane ----
__global__ __launch_bounds__(256) void k_bnstats(
        const float* __restrict__ out, float* __restrict__ bn_sum,
        float* __restrict__ bn_sumsq) {
    int wave = threadIdx.x >> 6;
    int lane = threadIdx.x & 63;
    if (lane >= H / 2) return;
    float2 s = make_float2(0.0f, 0.0f), ss = make_float2(0.0f, 0.0f);
    for (int n = blockIdx.x * 4 + wave; n < N_ENT; n += gridDim.x * 4) {
        float2 v = ((const float2*)(out + (size_t)n * H))[lane];
        s.x += v.x; s.y += v.y;
        ss.x += v.x * v.x; ss.y += v.y * v.y;
    }
    atomicAdd(bn_sum + 2 * lane + 0, s.x);
    atomicAdd(bn_sum + 2 * lane + 1, s.y);
    atomicAdd(bn_sumsq + 2 * lane + 0, ss.x);
    atomicAdd(bn_sumsq + 2 * lane + 1, ss.y);
}

// ---- apply BN (batch stats) + tanh, float2 per thread ----
__global__ __launch_bounds__(256) void k_bnapply(
        float* __restrict__ out, const float* __restrict__ bn_sum,
        const float* __restrict__ bn_sumsq, const float* __restrict__ gamma,
        const float* __restrict__ beta) {
    int t = blockIdx.x * 256 + threadIdx.x;        // float2 index
    if (t >= N_ENT * H / 2) return;
    int c2 = t % (H / 2);                          // dims 2*c2, 2*c2+1
    const float inv_n = 1.0f / (float)N_ENT;
    float2 v = ((const float2*)out)[t];
    float mu0 = bn_sum[2 * c2 + 0] * inv_n;
    float mu1 = bn_sum[2 * c2 + 1] * inv_n;
    float var0 = bn_sumsq[2 * c2 + 0] * inv_n - mu0 * mu0;
    float var1 = bn_sumsq[2 * c2 + 1] * inv_n - mu1 * mu1;
    float x0 = (v.x - mu0) * rsqrtf(var0 + BN_EPS) * gamma[2 * c2 + 0] + beta[2 * c2 + 0];
    float x1 = (v.y - mu1) * rsqrtf(var1 + BN_EPS) * gamma[2 * c2 + 1] + beta[2 * c2 + 1];
    ((float2*)out)[t] = make_float2(tanhf(x0), tanhf(x1));
}

extern "C" void kernel_launch(void* const* d_in, const int* in_sizes, int n_in,
                              void* d_out, int out_size, void* d_ws, size_t ws_size,
                              hipStream_t stream) {
    const float* ent   = (const float*)d_in[0];   // [50000,96]
    const float* rel   = (const float*)d_in[1];   // [500,96]
    const float* W     = (const float*)d_in[2];   // [96,96]
    const float* gamma = (const float*)d_in[3];   // [96]
    const float* beta  = (const float*)d_in[4];   // [96]
    const int* rel_id  = (const int*)d_in[5];     // [800000]
    const int* dst     = (const int*)d_in[6];     // [800000]
    float* out = (float*)d_out;                   // [50000,96] fp32

    // ws layout (4B units):
    // pay int2[E] (2E) | row_ptr [N] |
    // ZERO{ deg [N] | cursor [N] | bn_sum [H] | bn_sumsq [H] } |
    // relW [500*96] | blk_sum [NBLK]
    float* ws       = (float*)d_ws;
    int2*  pay      = (int2*)ws;
    int*   row_ptr  = (int*)(ws + 2 * N_EDGE);
    int*   zbase    = (int*)(ws + 2 * N_EDGE + N_ENT);
    int*   deg      = zbase;
    int*   cursor   = zbase + N_ENT;
    float* bn_sum   = (float*)(zbase + 2 * N_ENT);
    float* bn_sumsq = bn_sum + H;
    float* relW     = bn_sumsq + H;
    int*   blk_sum  = (int*)(relW + N_REL * H);

    const int zcount = 2 * N_ENT + 2 * H;
    k_zero<<<(zcount + 255) / 256, 256, 0, stream>>>((unsigned*)zbase, zcount);

    k_relw <<<(N_REL * H + 255) / 256, 256, 0, stream>>>(rel, W, relW);
    k_hist <<<(N_EDGE / 4 + 255) / 256, 256, 0, stream>>>(dst, deg);
    k_scan1<<<NBLK, SCAN_B, 0, stream>>>(deg, row_ptr, blk_sum);
    k_scan2<<<1, 64, 0, stream>>>(blk_sum);
    k_scan3<<<NBLK, SCAN_B, 0, stream>>>(row_ptr, blk_sum);
    k_score_bucket<<<(N_EDGE * 8 + 255) / 256, 256, 0, stream>>>(
        ent, rel, rel_id, dst, row_ptr, cursor, pay);
    k_node<<<(N_ENT * 64 + 255) / 256, 256, 0, stream>>>(
        pay, row_ptr, deg, relW, out);
    k_bnstats<<<128, 256, 0, stream>>>(out, bn_sum, bn_sumsq);
    k_bnapply<<<(N_ENT * H / 2 + 255) / 256, 256, 0, stream>>>(
        out, bn_sum, bn_sumsq, gamma, beta);
}